// Round 8
// baseline (69.155 us; speedup 1.0000x reference)
//
#include <hip/hip_runtime.h>

#define BATCH 64
#define N_IN  2048
#define NN    512
#define NCH   64          // n columns per block
#define THREADS 1024
#define ALPHA 0.995f
#define BETA  0.975f
#define V_TH  2.0f

typedef float f32x4 __attribute__((ext_vector_type(4)));

__global__ __launch_bounds__(THREADS, 8)   // cap VGPR<=64: 2 blocks/CU, 32 waves/CU
void fused_step(const float* __restrict__ x,
                const float* __restrict__ v,
                const float* __restrict__ z,
                const float* __restrict__ z_out,
                const float* __restrict__ w,
                float* __restrict__ out)
{
    const int b    = blockIdx.y;
    const int nb   = blockIdx.x * NCH;
    const int tid  = threadIdx.x;
    const int nl   = tid & 15;   // float4 column within the 64-wide n chunk
    const int kk   = tid >> 4;   // k-row group 0..63
    const int wid  = tid >> 6;   // wave 0..15
    const int lane = tid & 63;

    __shared__ float  zlds[NN];        // z_out_new for this batch (2 KB)
    __shared__ float4 wpart[16][16];   // per-wave drive1 partials [wave][nl] (4 KB)
    __shared__ float4 d1s[16];         // final drive1 (256 B)
    __shared__ float  red2[THREADS];   // drive2 partials (4 KB)

    // ---- z_out_new = BETA * z_out + z  (full row needed for the LOO gather)
    for (int i = tid; i < NN; i += THREADS)
        zlds[i] = BETA * z_out[b * NN + i] + z[b * NN + i];

    // ---- drive1 = sum_k x[b,k,n] * w[k,n]
    // x is streamed ONCE and never reused -> non-temporal loads keep the
    // 268 MB cyclic stream from thrashing the 256 MB L3 (x is 12 MB too big).
    const f32x4* __restrict__ x4 = (const f32x4*)(x + (size_t)b * N_IN * NN + nb);
    const float4* __restrict__ w4 = (const float4*)(w + nb);
    const f32x4*  xp = x4 + (size_t)kk * (NN / 4) + nl;
    const float4* wp = w4 + (size_t)kk * (NN / 4) + nl;
    const size_t kstride = (size_t)64 * (NN / 4);   // 64 k-rows per step

    float4 acc = make_float4(0.f, 0.f, 0.f, 0.f);
#pragma unroll 2
    for (int i = 0; i < 8; ++i) {
        f32x4 xv[4];
        float4 wvv[4];
#pragma unroll
        for (int u = 0; u < 4; ++u) xv[u]  = __builtin_nontemporal_load(xp + u * kstride);
#pragma unroll
        for (int u = 0; u < 4; ++u) wvv[u] = wp[u * kstride];   // cached: L2-hot
#pragma unroll
        for (int u = 0; u < 4; ++u) {
            acc.x += xv[u].x * wvv[u].x;
            acc.y += xv[u].y * wvv[u].y;
            acc.z += xv[u].z * wvv[u].z;
            acc.w += xv[u].w * wvv[u].w;
        }
        xp += 4 * kstride;
        wp += 4 * kstride;
    }

    // ---- in-wave reduce over the 4 k-groups (lanes l, l+16, l+32, l+48)
#pragma unroll
    for (int off = 32; off >= 16; off >>= 1) {
        acc.x += __shfl_down(acc.x, off);
        acc.y += __shfl_down(acc.y, off);
        acc.z += __shfl_down(acc.z, off);
        acc.w += __shfl_down(acc.w, off);
    }
    if (lane < 16) wpart[wid][lane] = acc;
    __syncthreads();   // covers zlds + wpart

    // ---- drive2 = sum_j z_out_new[b, j+(j>=n)] * w[N_IN+j, n]  (all threads)
    const int n_loc = tid & 63;
    const int n     = nb + n_loc;
    const int jg    = tid >> 6;          // 16 j-interleave groups
    float d2 = 0.f;
    for (int j = jg; j < NN - 1; j += 16)
        d2 += zlds[j + (j >= n)] * w[(size_t)(N_IN + j) * NN + n];
    red2[tid] = d2;

    // ---- drive1 column sums (threads 0..15, concurrent with other waves' drive2)
    if (tid < 16) {
        float4 s = wpart[0][tid];
#pragma unroll
        for (int ww = 1; ww < 16; ++ww) {
            const float4 o = wpart[ww][tid];
            s.x += o.x; s.y += o.y; s.z += o.z; s.w += o.w;
        }
        d1s[tid] = s;
    }
    __syncthreads();

    // ---- epilogue
    if (tid < 64) {
        const float d1 = ((const float*)d1s)[n_loc];
        float d2s = 0.f;
#pragma unroll
        for (int g = 0; g < 16; ++g) d2s += red2[n_loc + 64 * g];
        const float vv = v[b * NN + n];
        const float zz = z[b * NN + n];
        const float v_new = ALPHA * vv + d1 + d2s - V_TH * zz;
        out[b * NN + n]                  = v_new;
        out[BATCH * NN + b * NN + n]     = (v_new - V_TH > 0.f) ? 1.f : 0.f;
        out[2 * BATCH * NN + b * NN + n] = zlds[n];
    }
}

extern "C" void kernel_launch(void* const* d_in, const int* in_sizes, int n_in,
                              void* d_out, int out_size, void* d_ws, size_t ws_size,
                              hipStream_t stream) {
    (void)in_sizes; (void)n_in; (void)out_size; (void)d_ws; (void)ws_size;
    const float* x     = (const float*)d_in[0];
    const float* v     = (const float*)d_in[1];
    const float* z     = (const float*)d_in[2];
    const float* z_out = (const float*)d_in[3];
    const float* w     = (const float*)d_in[4];
    float* out = (float*)d_out;

    dim3 grid(NN / NCH, BATCH);   // 8 x 64 = 512 blocks, 2/CU, 32 waves/CU
    fused_step<<<grid, THREADS, 0, stream>>>(x, v, z, z_out, w, out);
}

// Round 9
// 53.661 us; speedup vs baseline: 1.2887x; 1.2887x over previous
//
#include <hip/hip_runtime.h>

#define BATCH 64
#define N_IN  2048
#define NN    512
#define NCH   64          // n columns per block (proven 256B-segment geometry)
#define G     4           // batches per block (w amortization)
#define KR    4           // k-ranges of 512 rows
#define ALPHA 0.995f
#define BETA  0.975f
#define V_TH  2.0f

// ---------------- K1: drive1 partials; w loaded once per G batches ----------------
// grid = (nc 0..7, bq 0..15, kr 0..3) = 512 blocks x 1024 thr -> 2/CU, 32 waves/CU
__global__ __launch_bounds__(1024, 8)
void k1_drive1(const float* __restrict__ x,
               const float* __restrict__ w,
               float4* __restrict__ ws)
{
    const int nc  = blockIdx.x;          // n-chunk 0..7
    const int b0  = blockIdx.y * G;      // batch group
    const int kr  = blockIdx.z;          // k-range 0..3
    const int tid = threadIdx.x;
    const int nl  = tid & 15;            // float4 col within 64-col chunk
    const int kk  = tid >> 4;            // 0..63
    const int wid  = tid >> 6;
    const int lane = tid & 63;

    const float4* __restrict__ x4 = (const float4*)x;
    const float4* __restrict__ w4 = (const float4*)w;
    const int    c4    = nc * 16 + nl;           // float4 column in 128-wide row
    const int    kbase = kr * 512 + kk;

    size_t xoff[G];
#pragma unroll
    for (int g = 0; g < G; ++g)
        xoff[g] = ((size_t)(b0 + g) * N_IN + kbase) * 128 + c4;
    size_t woff = (size_t)kbase * 128 + c4;

    float4 acc[G];
#pragma unroll
    for (int g = 0; g < G; ++g) acc[g] = make_float4(0.f, 0.f, 0.f, 0.f);

    const size_t kstep = (size_t)64 * 128;       // 64 k-rows
#pragma unroll 1
    for (int i = 0; i < 8; ++i) {                // 8 x 64 = 512 k-rows
        float4 xv[G];
#pragma unroll
        for (int g = 0; g < G; ++g) xv[g] = x4[xoff[g]];   // HBM streams first
        const float4 wv = w4[woff];                        // cache-hot second
#pragma unroll
        for (int g = 0; g < G; ++g) {
            acc[g].x += xv[g].x * wv.x;
            acc[g].y += xv[g].y * wv.y;
            acc[g].z += xv[g].z * wv.z;
            acc[g].w += xv[g].w * wv.w;
        }
#pragma unroll
        for (int g = 0; g < G; ++g) xoff[g] += kstep;
        woff += kstep;
    }

    // in-wave reduce over the 4 kk-subgroups (lane strides 32,16)
#pragma unroll
    for (int off = 32; off >= 16; off >>= 1) {
#pragma unroll
        for (int g = 0; g < G; ++g) {
            acc[g].x += __shfl_down(acc[g].x, off);
            acc[g].y += __shfl_down(acc[g].y, off);
            acc[g].z += __shfl_down(acc[g].z, off);
            acc[g].w += __shfl_down(acc[g].w, off);
        }
    }

    __shared__ float4 wpart[16][G][16];          // 16 KB
    if (lane < 16) {
#pragma unroll
        for (int g = 0; g < G; ++g) wpart[wid][g][lane] = acc[g];
    }
    __syncthreads();

    if (tid < 64) {                              // (g, c) = (tid>>4, tid&15)
        const int g = tid >> 4, c = tid & 15;
        float4 s = wpart[0][g][c];
#pragma unroll
        for (int ww = 1; ww < 16; ++ww) {
            const float4 o = wpart[ww][g][c];
            s.x += o.x; s.y += o.y; s.z += o.z; s.w += o.w;
        }
        ws[((size_t)kr * BATCH + b0 + g) * 128 + nc * 16 + c] = s;
    }
}

// ---------------- K2: ws partial-sum + LOO drive2 + epilogue (R6-validated) ----------------
__global__ __launch_bounds__(1024)
void k2_finish(const float* __restrict__ v,
               const float* __restrict__ z,
               const float* __restrict__ z_out,
               const float* __restrict__ w,
               const float* __restrict__ ws,
               float* __restrict__ out)
{
    const int nc  = blockIdx.x;          // 0..7
    const int b   = blockIdx.y;          // 0..63
    const int nb  = nc * 64;
    const int tid = threadIdx.x;

    __shared__ float zlds[NN];
    __shared__ float r2[1024];

    if (tid < NN)
        zlds[tid] = BETA * z_out[b * NN + tid] + z[b * NN + tid];
    __syncthreads();

    const int n_loc = tid & 63;
    const int n     = nb + n_loc;
    const int jg    = tid >> 6;          // 0..15
    float d2 = 0.f;
#pragma unroll 4
    for (int j = jg; j < NN - 1; j += 16)
        d2 += zlds[j + (j >= n)] * w[(size_t)(N_IN + j) * NN + n];
    r2[tid] = d2;
    __syncthreads();

    if (tid < 64) {
        float d1 = 0.f;
#pragma unroll
        for (int kr = 0; kr < KR; ++kr)
            d1 += ws[((size_t)kr * BATCH + b) * NN + n];
        float d2s = 0.f;
#pragma unroll
        for (int g = 0; g < 16; ++g) d2s += r2[g * 64 + n_loc];
        const float vv    = v[b * NN + n];
        const float zz    = z[b * NN + n];
        const float v_new = ALPHA * vv + d1 + d2s - V_TH * zz;
        out[b * NN + n]                  = v_new;
        out[BATCH * NN + b * NN + n]     = (v_new - V_TH > 0.f) ? 1.f : 0.f;
        out[2 * BATCH * NN + b * NN + n] = zlds[n];
    }
}

extern "C" void kernel_launch(void* const* d_in, const int* in_sizes, int n_in,
                              void* d_out, int out_size, void* d_ws, size_t ws_size,
                              hipStream_t stream) {
    (void)in_sizes; (void)n_in; (void)out_size; (void)ws_size;
    const float* x     = (const float*)d_in[0];
    const float* v     = (const float*)d_in[1];
    const float* z     = (const float*)d_in[2];
    const float* z_out = (const float*)d_in[3];
    const float* w     = (const float*)d_in[4];
    float* out = (float*)d_out;
    float* wsf = (float*)d_ws;           // KR*64*512 floats = 512 KB

    dim3 g1(8, BATCH / G, KR);           // 512 blocks
    k1_drive1<<<g1, 1024, 0, stream>>>(x, w, (float4*)wsf);
    dim3 g2(8, BATCH);                   // 512 blocks
    k2_finish<<<g2, 1024, 0, stream>>>(v, z, z_out, w, wsf, out);
}

// Round 10
// 53.489 us; speedup vs baseline: 1.2929x; 1.0032x over previous
//
#include <hip/hip_runtime.h>

#define BATCH 64
#define N_IN  2048
#define NN    512
#define G     4           // batches per block (w amortization)
#define ALPHA 0.995f
#define BETA  0.975f
#define V_TH  2.0f

// ---------------- K1 (primary): contiguous full-row streaming, w amortized x4 ----
// grid (kr 0..31, bq 0..15) = 512 blocks x 1024 thr -> 2/CU, 32 waves/CU.
// Each block: 64 k-rows x all 512 cols x G batches. Wave-load = 1 KB contiguous.
// linear_id % 8 == kr % 8 -> all 16 sharers of a w-slab on one XCD (L2-hot).
__global__ __launch_bounds__(1024, 8)
void k1_drive1(const float* __restrict__ x,
               const float* __restrict__ w,
               float4* __restrict__ ws)
{
    const int kr  = blockIdx.x;          // 0..31
    const int b0  = blockIdx.y * G;
    const int tid = threadIdx.x;
    const int c4  = tid & 127;           // float4 column 0..127
    const int kl  = tid >> 7;            // 0..7

    const float4* __restrict__ x4 = (const float4*)x;
    const float4* __restrict__ w4 = (const float4*)w;
    const int k0 = kr * 64 + kl;

    size_t xoff[G];
#pragma unroll
    for (int g = 0; g < G; ++g)
        xoff[g] = ((size_t)(b0 + g) * N_IN + k0) * 128 + c4;
    size_t woff = (size_t)k0 * 128 + c4;
    const size_t kstep = 8 * 128;        // 8 k-rows

    float4 acc[G];
#pragma unroll
    for (int g = 0; g < G; ++g) acc[g] = make_float4(0.f, 0.f, 0.f, 0.f);

#pragma unroll 2
    for (int i = 0; i < 8; ++i) {        // 8 x 8 = 64 k-rows
        float4 xv[G];
#pragma unroll
        for (int g = 0; g < G; ++g) xv[g] = x4[xoff[g]];   // HBM streams first
        const float4 wv = w4[woff];                        // L2-hot second
#pragma unroll
        for (int g = 0; g < G; ++g) {
            acc[g].x += xv[g].x * wv.x;
            acc[g].y += xv[g].y * wv.y;
            acc[g].z += xv[g].z * wv.z;
            acc[g].w += xv[g].w * wv.w;
        }
#pragma unroll
        for (int g = 0; g < G; ++g) xoff[g] += kstep;
        woff += kstep;
    }

    // cross-kl reduction: red[g][kl][c4], lanes stride 16B -> free 2-way banks
    __shared__ float4 red[G][8][128];    // 64 KB
#pragma unroll
    for (int g = 0; g < G; ++g) red[g][kl][c4] = acc[g];
    __syncthreads();

    if (tid < 512) {                     // (g, c) = (tid>>7, tid&127)
        const int g = tid >> 7, c = tid & 127;
        float4 s = red[g][0][c];
#pragma unroll
        for (int l = 1; l < 8; ++l) {
            const float4 o = red[g][l][c];
            s.x += o.x; s.y += o.y; s.z += o.z; s.w += o.w;
        }
        ws[((size_t)kr * BATCH + b0 + g) * 128 + c] = s;
    }
}

// ---------------- K1 fallback (R9-proven, 1 MB ws) ----------------
#define KRF 4
__global__ __launch_bounds__(1024, 8)
void k1_fallback(const float* __restrict__ x,
                 const float* __restrict__ w,
                 float4* __restrict__ ws)
{
    const int nc  = blockIdx.x;
    const int b0  = blockIdx.y * G;
    const int kr  = blockIdx.z;
    const int tid = threadIdx.x;
    const int nl  = tid & 15;
    const int kk  = tid >> 4;
    const int wid  = tid >> 6;
    const int lane = tid & 63;

    const float4* __restrict__ x4 = (const float4*)x;
    const float4* __restrict__ w4 = (const float4*)w;
    const int c4    = nc * 16 + nl;
    const int kbase = kr * 512 + kk;

    size_t xoff[G];
#pragma unroll
    for (int g = 0; g < G; ++g)
        xoff[g] = ((size_t)(b0 + g) * N_IN + kbase) * 128 + c4;
    size_t woff = (size_t)kbase * 128 + c4;

    float4 acc[G];
#pragma unroll
    for (int g = 0; g < G; ++g) acc[g] = make_float4(0.f, 0.f, 0.f, 0.f);

    const size_t kstep = (size_t)64 * 128;
#pragma unroll 2
    for (int i = 0; i < 8; ++i) {
        float4 xv[G];
#pragma unroll
        for (int g = 0; g < G; ++g) xv[g] = x4[xoff[g]];
        const float4 wv = w4[woff];
#pragma unroll
        for (int g = 0; g < G; ++g) {
            acc[g].x += xv[g].x * wv.x;
            acc[g].y += xv[g].y * wv.y;
            acc[g].z += xv[g].z * wv.z;
            acc[g].w += xv[g].w * wv.w;
        }
#pragma unroll
        for (int g = 0; g < G; ++g) xoff[g] += kstep;
        woff += kstep;
    }

#pragma unroll
    for (int off = 32; off >= 16; off >>= 1) {
#pragma unroll
        for (int g = 0; g < G; ++g) {
            acc[g].x += __shfl_down(acc[g].x, off);
            acc[g].y += __shfl_down(acc[g].y, off);
            acc[g].z += __shfl_down(acc[g].z, off);
            acc[g].w += __shfl_down(acc[g].w, off);
        }
    }

    __shared__ float4 wpart[16][G][16];
    if (lane < 16) {
#pragma unroll
        for (int g = 0; g < G; ++g) wpart[wid][g][lane] = acc[g];
    }
    __syncthreads();

    if (tid < 64) {
        const int g = tid >> 4, c = tid & 15;
        float4 s = wpart[0][g][c];
#pragma unroll
        for (int ww = 1; ww < 16; ++ww) {
            const float4 o = wpart[ww][g][c];
            s.x += o.x; s.y += o.y; s.z += o.z; s.w += o.w;
        }
        ws[((size_t)kr * BATCH + b0 + g) * 128 + nc * 16 + c] = s;
    }
}

// ---------------- K2: ws partial-sum + LOO drive2 + epilogue ----------------
template <int KRV>
__global__ __launch_bounds__(1024)
void k2_finish(const float* __restrict__ v,
               const float* __restrict__ z,
               const float* __restrict__ z_out,
               const float* __restrict__ w,
               const float* __restrict__ ws,
               float* __restrict__ out)
{
    const int nc  = blockIdx.x;
    const int b   = blockIdx.y;
    const int nb  = nc * 64;
    const int tid = threadIdx.x;

    __shared__ float zlds[NN];
    __shared__ float r2[1024];

    if (tid < NN)
        zlds[tid] = BETA * z_out[b * NN + tid] + z[b * NN + tid];
    __syncthreads();

    const int n_loc = tid & 63;
    const int n     = nb + n_loc;
    const int jg    = tid >> 6;
    float d2 = 0.f;
#pragma unroll 4
    for (int j = jg; j < NN - 1; j += 16)
        d2 += zlds[j + (j >= n)] * w[(size_t)(N_IN + j) * NN + n];
    r2[tid] = d2;
    __syncthreads();

    if (tid < 64) {
        float d1 = 0.f;
#pragma unroll
        for (int kr = 0; kr < KRV; ++kr)
            d1 += ws[((size_t)kr * BATCH + b) * NN + n];
        float d2s = 0.f;
#pragma unroll
        for (int g = 0; g < 16; ++g) d2s += r2[g * 64 + n_loc];
        const float vv    = v[b * NN + n];
        const float zz    = z[b * NN + n];
        const float v_new = ALPHA * vv + d1 + d2s - V_TH * zz;
        out[b * NN + n]                  = v_new;
        out[BATCH * NN + b * NN + n]     = (v_new - V_TH > 0.f) ? 1.f : 0.f;
        out[2 * BATCH * NN + b * NN + n] = zlds[n];
    }
}

extern "C" void kernel_launch(void* const* d_in, const int* in_sizes, int n_in,
                              void* d_out, int out_size, void* d_ws, size_t ws_size,
                              hipStream_t stream) {
    (void)in_sizes; (void)n_in; (void)out_size;
    const float* x     = (const float*)d_in[0];
    const float* v     = (const float*)d_in[1];
    const float* z     = (const float*)d_in[2];
    const float* z_out = (const float*)d_in[3];
    const float* w     = (const float*)d_in[4];
    float* out = (float*)d_out;
    float* wsf = (float*)d_ws;

    const size_t need32 = (size_t)32 * BATCH * NN * sizeof(float);   // 4 MB
    if (ws_size >= need32) {
        dim3 g1(32, BATCH / G);              // 512 blocks
        k1_drive1<<<g1, 1024, 0, stream>>>(x, w, (float4*)wsf);
        dim3 g2(8, BATCH);
        k2_finish<32><<<g2, 1024, 0, stream>>>(v, z, z_out, w, wsf, out);
    } else {
        dim3 g1(8, BATCH / G, KRF);          // 512 blocks (R9 geometry)
        k1_fallback<<<g1, 1024, 0, stream>>>(x, w, (float4*)wsf);
        dim3 g2(8, BATCH);
        k2_finish<KRF><<<g2, 1024, 0, stream>>>(v, z, z_out, w, wsf, out);
    }
}